// Round 2
// baseline (118.686 us; speedup 1.0000x reference)
//
#include <hip/hip_runtime.h>

#define BB 256
#define LL 512

typedef float nfloat4 __attribute__((ext_vector_type(4)));
typedef int   nint4   __attribute__((ext_vector_type(4)));

// ---------------------------------------------------------------------------
// Single fused kernel per (batch, dir):
//   packed histogram -> SCAN-BASED dedup (no hash/CAS: scan hist's 2000
//   entries = distinct ids; count values rank-mapped (<=63, provable) ->
//   rank-pair key < 4096 -> direct-mapped LDS table; x-presence = idempotent
//   plain store, c-multiplicity = one atomicAdd per distinct id) ->
//   CANONICAL pair merge (encode MLP is symmetric: feat = T(a)+T(b), so
//   (a,b) == (b,a); ~30-40% fewer rows) -> per-block encode table ->
//   linear cross-attn on deduped rows -> LN -> scatter to 512 positions.
// Phase B computes at = (qh . M_hat) . Wo via two broadcast-dots (no G phase).
// ~12 barriers/block; the serialized CAS insert phase is gone entirely.
// ---------------------------------------------------------------------------
__global__ __launch_bounds__(256, 2) void k_all(
    const int* __restrict__ src, const int* __restrict__ dst,
    const float* __restrict__ w1, const float* __restrict__ b1,
    const float* __restrict__ w2, const float* __restrict__ b2,
    const float* __restrict__ Wq, const float* __restrict__ Wk,
    const float* __restrict__ Wv, const float* __restrict__ Wo,
    const float* __restrict__ bo, const float* __restrict__ lng,
    const float* __restrict__ lnb, float* __restrict__ out) {
  // ---- LDS layout (byte offsets; regions reused across phases) ----
  // [0,16384)      hist(2000 int packed: src lo16 | dst hi16) ->
  //                Phase A pA/vA (2x32x64 f) -> Phase B row chunk (64x64 f)
  // [16384,32768)  dmapc (4096 int, c-side mult) -> tabL 64x64 f
  // [32768,49152)  dmapx (4096 int, x-side presence->idx); region becomes
  // [32768,50176)  Mg: MT (64 x stride-68 f) at end of Phase A
  // [50176,58368)  xkey | ckey | cmult | pidxl (512 ints each)
  // [58368,60680)  cflag(513)->cmap + clist(64)
  // [60688,63760)  fbF: featb | qbuf | sred/tbuf (256 f each)
  // [63760,63772)  npp[3]
  __shared__ __align__(16) char smem[63776];
  int*   hist  = (int*)smem;
  float* poolF = (float*)smem;
  int*   dmapc = (int*)(smem + 16384);
  float* tabL  = (float*)(smem + 16384);   // 64 rows x 64
  int*   dmapx = (int*)(smem + 32768);
  float* Mg    = (float*)(smem + 32768);   // MT, stride 68
  int*   xkey  = (int*)(smem + 50176);
  int*   ckey  = (int*)(smem + 52224);
  int*   cmult = (int*)(smem + 54272);
  int*   pidxl = (int*)(smem + 56320);
  int*   cflag = (int*)(smem + 58368);     // 513 ints -> becomes cmap
  int*   clist = (int*)(smem + 60424);     // 64 ints
  float* fbF   = (float*)(smem + 60688);   // featb 0..255|qbuf 256..511|sred 512..767
  int*   npp   = (int*)(smem + 63760);     // [0]=Pc [1]=Px [2]=nc

  int bd = blockIdx.x, b = bd >> 1, dir = bd & 1;
  int tid = threadIdx.x, tx = tid & 63, ty = tid >> 6;
  int e0 = ty * 16;

  // ---- phase 0: id loads + hoisted w2-column loads + vec4 zero ----
  const int* s = src + b * LL;
  const int* d = dst + b * LL;
  int sid0 = s[tid], sid1 = s[tid + 256];
  int did0 = d[tid], did1 = d[tid + 256];

  float wcA[64], wcB[64];
#pragma unroll
  for (int f = 0; f < 64; ++f) wcA[f] = w2[f * 64 + tx];   // w2 column tx
  float w1v = w1[tx], b1v = b1[tx], b2v = b2[tx];

  {
    nint4 z4 = {0, 0, 0, 0};
    nint4* h4z = (nint4*)hist;          // 2000 ints = 500 vec4
    for (int i = tid; i < 500; i += 256) h4z[i] = z4;
    nint4* dm4 = (nint4*)dmapc;         // dmapc+dmapx contiguous: 8192 ints
    for (int i = tid; i < 2048; i += 256) dm4[i] = z4;
    nint4* cf4 = (nint4*)cflag;         // 512 ints
    if (tid < 128) cf4[tid] = z4;
    if (tid == 0) cflag[512] = 0;
    if (tid < 3) npp[tid] = 0;
  }
  __syncthreads();

  // ---- packed histogram: one word per id, both sides ----
  atomicAdd(&hist[sid0], 1);      atomicAdd(&hist[sid1], 1);
  atomicAdd(&hist[did0], 65536);  atomicAdd(&hist[did1], 65536);
  __syncthreads();

  int x0 = dir ? did0 : sid0, x1 = dir ? did1 : sid1;

  // ---- flag distinct count values (plain idempotent stores) ----
  for (int i = tid; i < 2000; i += 256) {
    int hv = hist[i];
    if (i != 0 && hv != 0) { cflag[hv & 0xffff] = 1; cflag[hv >> 16] = 1; }
  }
  if (tid == 0) cflag[0] = 1;   // id-0 pair is (0,0)
  __syncthreads();

  // ---- compact count values -> rank map (provably <= 63: 31+31+zero) ----
  for (int c = tid; c < 513; c += 256) {
    if (cflag[c]) {
      int idx = atomicAdd(&npp[2], 1);
      clist[idx] = c;
      cflag[c] = idx;                    // cflag becomes cmap
    }
  }
  __syncthreads();

  // ---- scan-based pair insert: one pass over distinct ids ----
  // canonical unordered pair {cs,cd}; feat = T(a)+T(b) is symmetric.
  for (int i = tid; i < 2000; i += 256) {
    int hv = hist[i];
    if (i == 0 || hv == 0) continue;
    int cs = hv & 0xffff, cd = hv >> 16;
    int k = cflag[min(cs, cd)] * 64 + cflag[max(cs, cd)];
    int ox = dir ? cd : cs;   // own count in x-list
    int oc = dir ? cs : cd;   // own count in c-list
    if (ox) dmapx[k] = 1;                 // presence: idempotent store
    if (oc) atomicAdd(&dmapc[k], oc);     // multiplicity: positions = count
  }
  if (tid == 0) {            // id 0: appearances forced to (0,0)
    int hv = hist[0];
    int cs = hv & 0xffff, cd = hv >> 16;
    int k00 = cflag[0] * 65;
    int ox = dir ? cd : cs, oc = dir ? cs : cd;
    if (ox) dmapx[k00] = 1;
    if (oc) atomicAdd(&dmapc[k00], oc);
  }
  __syncthreads();

  // ---- compact both direct-mapped tables (keys already in rank form) ----
  for (int i = tid; i < 4096; i += 256) {
    int v = dmapc[i];
    if (v) { int idx = atomicAdd(&npp[0], 1); ckey[idx] = i; cmult[idx] = v; }
    int xv = dmapx[i];
    if (xv) { int idx = atomicAdd(&npp[1], 1); xkey[idx] = i; dmapx[i] = idx; }
  }
  __syncthreads();
  int Pc = npp[0], Px = npp[1], nc = npp[2];

  // ---- pidxl gather (no atomics) + encode table build, one phase ----
  {
    int hvx0 = (x0 == 0) ? 0 : hist[x0];
    int hvx1 = (x1 == 0) ? 0 : hist[x1];
    int k0, k1;
    {
      int cs = hvx0 & 0xffff, cd = hvx0 >> 16;
      k0 = (x0 == 0) ? cflag[0] * 65 : cflag[min(cs, cd)] * 64 + cflag[max(cs, cd)];
    }
    {
      int cs = hvx1 & 0xffff, cd = hvx1 >> 16;
      k1 = (x1 == 0) ? cflag[0] * 65 : cflag[min(cs, cd)] * 64 + cflag[max(cs, cd)];
    }
    pidxl[tid]       = dmapx[k0];
    pidxl[tid + 256] = dmapx[k1];
  }
  // T(c)[g] = b2[g] + sum_f relu(c*w1[f]+b1[f]) * w2[f][g]  (dmapc dead)
  for (int i = ty; i < nc; i += 4) {
    float c = (float)clist[i];
    fbF[ty * 64 + tx] = fmaxf(c * w1v + b1v, 0.f);         // wave-local h row
    float acc = b2v;
    const float4* h4 = (const float4*)&fbF[ty * 64];
#pragma unroll
    for (int q = 0; q < 16; ++q) {
      float4 hv = h4[q];
      acc += hv.x * wcA[4 * q] + hv.y * wcA[4 * q + 1] + hv.z * wcA[4 * q + 2] + hv.w * wcA[4 * q + 3];
    }
    tabL[i * 64 + tx] = acc;
  }
  // load Wk / Wv columns while table settles
#pragma unroll
  for (int f = 0; f < 64; ++f) { wcA[f] = Wk[f * 64 + tx]; wcB[f] = Wv[f * 64 + tx]; }
  float macc[16];
#pragma unroll
  for (int e = 0; e < 16; ++e) macc[e] = 0.f;
  float sacc = 0.f;
  __syncthreads();   // tabL + pidxl ready; hist/dmapx regions now dead

  // ---- Phase A: M[d][e] = sum_j n_j exp(k_j[d]) v_j[e] / colsum ----
  float* pA = poolF;          // 32 x 64
  float* vA = poolF + 2048;   // 32 x 64
  for (int j0 = 0; j0 < Pc; j0 += 32) {
    int cN = min(32, Pc - j0);
    for (int j = ty; j < cN; j += 4) {
      int key = ckey[j0 + j];
      int ia = key >> 6, ib = key & 63;
      fbF[ty * 64 + tx] = tabL[ia * 64 + tx] + tabL[ib * 64 + tx];  // wave-local
      float kr = 0.f, vr = 0.f;
      const float4* fb4 = (const float4*)&fbF[ty * 64];
#pragma unroll
      for (int q = 0; q < 16; ++q) {
        float4 fv = fb4[q];
        kr += fv.x * wcA[4 * q] + fv.y * wcA[4 * q + 1] + fv.z * wcA[4 * q + 2] + fv.w * wcA[4 * q + 3];
        vr += fv.x * wcB[4 * q] + fv.y * wcB[4 * q + 1] + fv.z * wcB[4 * q + 2] + fv.w * wcB[4 * q + 3];
      }
      float p = __expf(kr) * (float)cmult[j0 + j];  // |kr| ~ O(10): safe fp32
      sacc += p;
      pA[j * 64 + tx] = p;
      vA[j * 64 + tx] = vr;
    }
    if (j0 + 32 >= Pc) fbF[512 + ty * 64 + tx] = sacc;  // fold sacc barrier
    __syncthreads();
    // thread (tx,ty) owns M[d=tx][e0..e0+15]
    for (int jj = 0; jj < cN; ++jj) {
      float pg = pA[jj * 64 + tx];
      const float4* vb4 = (const float4*)&vA[jj * 64 + e0];
#pragma unroll
      for (int q = 0; q < 4; ++q) {
        float4 vv = vb4[q];
        macc[4 * q]     += pg * vv.x; macc[4 * q + 1] += pg * vv.y;
        macc[4 * q + 2] += pg * vv.z; macc[4 * q + 3] += pg * vv.w;
      }
    }
    __syncthreads();
  }
  float inv = 1.f / (fbF[512 + tx] + fbF[576 + tx] + fbF[640 + tx] + fbF[704 + tx]);
  // MT[f][d] = M_hat[d][f] = M[d][f] * inv[d]   (alive through Phase B)
#pragma unroll
  for (int e = 0; e < 16; ++e) Mg[(e0 + e) * 68 + tx] = macc[e] * inv;
  // Wq + Wo columns into registers (wcA/wcB dead after Phase A)
#pragma unroll
  for (int f = 0; f < 64; ++f) { wcA[f] = Wq[f * 64 + tx]; wcB[f] = Wo[f * 64 + tx]; }
  float bov = bo[tx], lg = lng[tx], lb = lnb[tx];
  __syncthreads();   // MT visible

  // ---- Phase B: per distinct x pair -> output row; chunked scatter ----
  // at = (qh . M_hat) . Wo  -- two broadcast-dots.
  for (int i0 = 0; i0 < Px; i0 += 64) {
    int cN = min(64, Px - i0);
    for (int jj = ty; jj < cN; jj += 4) {
      int key = xkey[i0 + jj];
      int ia = key >> 6, ib = key & 63;
      float fv = tabL[ia * 64 + tx] + tabL[ib * 64 + tx];
      fbF[ty * 64 + tx] = fv;
      float qr = 0.f;
      const float4* fb4 = (const float4*)&fbF[ty * 64];
#pragma unroll
      for (int q = 0; q < 16; ++q) {
        float4 f4v = fb4[q];
        qr += f4v.x * wcA[4 * q] + f4v.y * wcA[4 * q + 1] + f4v.z * wcA[4 * q + 2] + f4v.w * wcA[4 * q + 3];
      }
      float p = __expf(qr);
      float sum = p;
#pragma unroll
      for (int off = 32; off >= 1; off >>= 1) sum += __shfl_xor(sum, off, 64);
      float qh = p / sum * 0.125f;   // softmax * F^-0.5
      fbF[256 + ty * 64 + tx] = qh;
      // stage 1: t[f=tx] = sum_d qh[d] * MT[tx][d]   (stride-68 b128, clean)
      float t = 0.f;
      const float4* qb4 = (const float4*)&fbF[256 + ty * 64];
      const float4* mt4 = (const float4*)&Mg[tx * 68];
#pragma unroll
      for (int q = 0; q < 16; ++q) {
        float4 qv = qb4[q];
        float4 mv = mt4[q];
        t += qv.x * mv.x + qv.y * mv.y + qv.z * mv.z + qv.w * mv.w;
      }
      fbF[512 + ty * 64 + tx] = t;   // sred region free in Phase B
      // stage 2: at[o=tx] = sum_f t[f] * Wo[f][tx]
      float at = 0.f;
      const float4* tb4 = (const float4*)&fbF[512 + ty * 64];
#pragma unroll
      for (int q = 0; q < 16; ++q) {
        float4 tv = tb4[q];
        at += tv.x * wcB[4 * q] + tv.y * wcB[4 * q + 1] + tv.z * wcB[4 * q + 2] + tv.w * wcB[4 * q + 3];
      }
      float r = fv + at + bov;
      float mu = r;
#pragma unroll
      for (int off = 32; off >= 1; off >>= 1) mu += __shfl_xor(mu, off, 64);
      mu *= (1.f / 64.f);
      float dv = r - mu;
      float var = dv * dv;
#pragma unroll
      for (int off = 32; off >= 1; off >>= 1) var += __shfl_xor(var, off, 64);
      var *= (1.f / 64.f);
      poolF[jj * 64 + tx] = dv * rsqrtf(var + 1e-5f) * lg + lb;
    }
    __syncthreads();
    const nfloat4* w4 = (const nfloat4*)poolF;
    nfloat4* out4 = (nfloat4*)(out + (size_t)(dir * BB + b) * (LL * 64));
    for (int idx = tid; idx < 512 * 16; idx += 256) {
      int l = idx >> 4, q = idx & 15;
      int pid = pidxl[l];
      if (pid >= i0 && pid < i0 + cN)
        __builtin_nontemporal_store(w4[(pid - i0) * 16 + q], &out4[l * 16 + q]);
    }
    __syncthreads();
  }
}

extern "C" void kernel_launch(void* const* d_in, const int* in_sizes, int n_in,
                              void* d_out, int out_size, void* d_ws, size_t ws_size,
                              hipStream_t stream) {
  const int* src  = (const int*)d_in[0];
  const int* dst  = (const int*)d_in[1];
  const float* w1 = (const float*)d_in[2];
  const float* b1 = (const float*)d_in[3];
  const float* w2 = (const float*)d_in[4];
  const float* b2 = (const float*)d_in[5];
  const float* Wq = (const float*)d_in[6];
  const float* Wk = (const float*)d_in[7];
  const float* Wv = (const float*)d_in[8];
  const float* Wo = (const float*)d_in[9];
  const float* bo = (const float*)d_in[10];
  const float* lng = (const float*)d_in[11];
  const float* lnb = (const float*)d_in[12];
  float* out = (float*)d_out;

  k_all<<<dim3(512), dim3(256), 0, stream>>>(src, dst, w1, b1, w2, b2,
                                             Wq, Wk, Wv, Wo, bo, lng, lnb, out);
}